// Round 4
// baseline (800.303 us; speedup 1.0000x reference)
//
#include <hip/hip_runtime.h>

#define NW 32
#define BATCH 2048
#define BIGF 1e9f

// One DPP min step: ctrl/row_mask as template params (must be ICEs).
// bound_ctrl=false => lanes with invalid source keep old value (min identity).
template <int CTRL, int ROW_MASK>
__device__ __forceinline__ float dpp_min_step(float x) {
    int xi = __float_as_int(x);
    int ti = __builtin_amdgcn_update_dpp(xi, xi, CTRL, ROW_MASK, 0xF, false);
    return fminf(x, __int_as_float(ti));
}

// Min over lanes 0..31 (lanes 32..63 must hold BIGF), wave-uniform result.
// row_shr 1,2,4,8 -> lane15=min(0..15), lane31=min(16..31);
// row_bcast:15 (rows 1,3) -> lane31=min(0..31). Read lane 31.
__device__ __forceinline__ float wave_min32(float x) {
    x = dpp_min_step<0x111, 0xF>(x); // row_shr:1
    x = dpp_min_step<0x112, 0xF>(x); // row_shr:2
    x = dpp_min_step<0x114, 0xF>(x); // row_shr:4
    x = dpp_min_step<0x118, 0xF>(x); // row_shr:8
    x = dpp_min_step<0x142, 0xA>(x); // row_bcast:15 -> rows 1,3
    return __int_as_float(__builtin_amdgcn_readlane(__float_as_int(x), 31));
}

__device__ __forceinline__ float readlane_f(float v, int lane) {
    return __int_as_float(__builtin_amdgcn_readlane(__float_as_int(v), lane));
}

// Uniform dynamic index into 32 register-resident floats: 5-level cndmask tree.
__device__ __forceinline__ float sel32(const float* cr, int i) {
    float s16[16], s8[8], s4[4], s2[2];
    const bool b0 = i & 1, b1 = i & 2, b2 = i & 4, b3 = i & 8, b4 = i & 16;
    #pragma unroll
    for (int m = 0; m < 16; ++m) s16[m] = b0 ? cr[2 * m + 1] : cr[2 * m];
    #pragma unroll
    for (int m = 0; m < 8; ++m)  s8[m]  = b1 ? s16[2 * m + 1] : s16[2 * m];
    #pragma unroll
    for (int m = 0; m < 4; ++m)  s4[m]  = b2 ? s8[2 * m + 1]  : s8[2 * m];
    #pragma unroll
    for (int m = 0; m < 2; ++m)  s2[m]  = b3 ? s4[2 * m + 1]  : s4[2 * m];
    return b4 ? s2[1] : s2[0];
}

__global__ __launch_bounds__(64) void floorplan_hungarian_kernel(
    const float* __restrict__ params_true,
    const float* __restrict__ params_pred,
    float* __restrict__ out)
{
    const int b    = blockIdx.x;
    const int lane = threadIdx.x;           // 0..63, one full wave

    __shared__ float cost[NW][NW + 1];      // padded rows: conflict-free
    __shared__ float featT[NW][9];
    __shared__ float featP[NW][9];

    // ---------------- Phase 1: per-wall features (1 wall per lane) -------------
    {
        const float* src = (lane < NW)
            ? (params_true + ((size_t)b * NW + lane) * 6)
            : (params_pred + ((size_t)b * NW + (lane - NW)) * 6);
        float sx = src[0], sy = src[1], ex = src[2], ey = src[3];
        float w  = src[4], prob = src[5];

        float dx = ex - sx, dy = ey - sy;
        float cx = (sx + ex) * 0.5f, cy = (sy + ey) * 0.5f;
        float len = sqrtf(dx * dx + dy * dy);
        float area = len * w;

        float smaller = fminf(w, len), bigger = fmaxf(w, len);
        float sr = (bigger > 0.0f) ? (smaller / bigger) : 0.0f;

        float px = dy, py = -dx;
        float pd = len;
        if (pd > 0.0f) { px /= pd; py /= pd; }
        px *= w * 0.5f; py *= w * 0.5f;
        float right = fmaxf(fmaxf(sx + px, sx - px), fmaxf(ex + px, ex - px));
        float top   = fmaxf(fmaxf(sy + py, sy - py), fmaxf(ey + py, ey - py));
        float bbw = fabsf((right - cx) * 2.0f);
        float bbh = fabsf((top   - cy) * 2.0f);
        float bba = bbw * bbh;
        float ar  = (bba > 0.001f) ? (area / bba) : 1.0f;

        float* f = (lane < NW) ? featT[lane] : featP[lane - NW];
        f[0] = cx;  f[1] = cy;  f[2] = area; f[3] = sr;
        f[4] = ar;  f[5] = bbw; f[6] = bbh;  f[7] = prob;
    }
    __syncthreads();

    // ---------------- Phase 2: 32x32 cost matrix (16 entries/lane) -------------
    for (int e = lane; e < NW * NW; e += 64) {
        int i = e >> 5, j = e & 31;
        float dcx = featT[i][0] - featP[j][0];
        float dcy = featT[i][1] - featP[j][1];
        float center_d = dcx * dcx + dcy * dcy;
        float da = featT[i][2] - featP[j][2];   float area_d  = da * da;
        float ds = featT[i][3] - featP[j][3];   float lwr_d   = ds * ds;
        float dr = featT[i][4] - featP[j][4];   float rot_d   = dr * dr;
        float dxw = featT[i][5] - featP[j][5];  float horiz_d = dxw * dxw;
        float dyh = featT[i][6] - featP[j][6];  float vert_d  = dyh * dyh;
        float probt = featT[i][7], probp = featP[j][7];
        float dp = probt - probp;               float prob_d  = dp * dp;
        float param_d = area_d + center_d + rot_d + horiz_d + vert_d + lwr_d;
        cost[i][j] = 10.0f * prob_d + param_d * probt;
    }
    __syncthreads();

    // Register-resident cost column: lane l holds cost[k][l&31] for k=0..31.
    // Bank = (33k + j) % 32 = (k+j) % 32 -> 2 lanes/bank across wave64 = free.
    float cr[NW];
    #pragma unroll
    for (int k = 0; k < NW; ++k) cr[k] = cost[k][lane & 31];

    // ---------------- Phase 3: Hungarian (JV SAP), one wave per batch ----------
    // lane j (<32) holds column-j state (v, spc, path, SC, row4col);
    // same lane also holds row-j state (u, col4row).
    const bool isCol = lane < NW;
    float v_col   = 0.0f;
    float u_row   = 0.0f;
    int   row4col = -1;
    int   col4row = -1;

    for (int i0 = 0; i0 < NW; ++i0) {
        bool  SCb   = !isCol;       // lanes >=32: permanently excluded
        float spc   = BIGF;
        int   path  = -1;
        unsigned srMask = 0;        // scalar bitmask of SR rows
        float minVal = 0.0f;        // scalar
        int   i = i0;               // scalar
        int   sink;

        while (true) {
            srMask |= (1u << i);
            float cij   = sel32(cr, i);                          // regs, no LDS
            float u_i   = readlane_f(u_row, i);                  // scalar
            float slack = minVal + cij - u_i - v_col;            // same assoc. as ref
            bool better = (!SCb) && (slack < spc);
            if (better) { spc = slack; path = i; }
            float spcRed = SCb ? BIGF : spc;                     // masked for argmin

            float mv = wave_min32(spcRed);                       // scalar min
            unsigned long long hit = __ballot(spcRed == mv);     // exact-bit match
            int j = __ffsll(hit) - 1;                            // lowest index tie-break
            minVal = mv;
            if (lane == j) SCb = true;
            int r = __builtin_amdgcn_readlane(row4col, j);       // scalar
            if (r < 0) { sink = j; break; }
            i = r;
        }

        // potential updates
        {
            int gidx = (col4row < 0) ? 0 : col4row;
            float spc_at_c4r = __shfl(spc, gidx);                // per-lane index
            bool in_SR = isCol && ((srMask >> (lane & 31)) & 1u);
            if (lane == i0)              u_row += minVal;
            else if (in_SR)              u_row += minVal - spc_at_c4r;
            if (isCol && SCb)            v_col -= (minVal - spc);
        }

        // augment along path (scalar walk)
        {
            int j = sink;
            while (true) {
                int ii = __builtin_amdgcn_readlane(path, j);
                if (lane == j) row4col = ii;
                int j_next = __builtin_amdgcn_readlane(col4row, ii);
                if (lane == ii) col4row = j;
                if (ii == i0) break;
                j = j_next;
            }
        }
    }

    // ---------------- Phase 4: loss = sum of assigned edge costs ---------------
    float myedge = (isCol && col4row >= 0) ? cost[lane][col4row] : 0.0f;
    #pragma unroll
    for (int off = 32; off >= 1; off >>= 1)
        myedge += __shfl_xor(myedge, off);
    if (lane == 0) out[b] = myedge;
}

extern "C" void kernel_launch(void* const* d_in, const int* in_sizes, int n_in,
                              void* d_out, int out_size, void* d_ws, size_t ws_size,
                              hipStream_t stream) {
    const float* params_true = (const float*)d_in[0];
    const float* params_pred = (const float*)d_in[1];
    float* out = (float*)d_out;
    floorplan_hungarian_kernel<<<BATCH, 64, 0, stream>>>(params_true, params_pred, out);
}

// Round 5
// 170.721 us; speedup vs baseline: 4.6878x; 4.6878x over previous
//
#include <hip/hip_runtime.h>

#define NW 32
#define BATCH 2048
#define BIGF 1e9f

// One DPP min step: ctrl/row_mask as template params (must be ICEs).
// bound_ctrl=false => lanes with invalid source keep old value (min identity).
template <int CTRL, int ROW_MASK>
__device__ __forceinline__ float dpp_min_step(float x) {
    int xi = __float_as_int(x);
    int ti = __builtin_amdgcn_update_dpp(xi, xi, CTRL, ROW_MASK, 0xF, false);
    return fminf(x, __int_as_float(ti));
}

// Min over lanes 0..31 (lanes 32..63 must hold BIGF), wave-uniform result.
__device__ __forceinline__ float wave_min32(float x) {
    x = dpp_min_step<0x111, 0xF>(x); // row_shr:1
    x = dpp_min_step<0x112, 0xF>(x); // row_shr:2
    x = dpp_min_step<0x114, 0xF>(x); // row_shr:4
    x = dpp_min_step<0x118, 0xF>(x); // row_shr:8
    x = dpp_min_step<0x142, 0xA>(x); // row_bcast:15 -> rows 1,3
    return __int_as_float(__builtin_amdgcn_readlane(__float_as_int(x), 31));
}

__device__ __forceinline__ float readlane_f(float v, int lane) {
    return __int_as_float(__builtin_amdgcn_readlane(__float_as_int(v), lane));
}

__global__ __launch_bounds__(64) void floorplan_hungarian_kernel(
    const float* __restrict__ params_true,
    const float* __restrict__ params_pred,
    float* __restrict__ out)
{
    const int b    = blockIdx.x;
    const int lane = threadIdx.x;           // 0..63, one full wave

    __shared__ float cost[NW][NW + 1];      // padded rows: conflict-free
    __shared__ float featT[NW][9];
    __shared__ float featP[NW][9];

    // ---------------- Phase 1: per-wall features (1 wall per lane) -------------
    {
        const float* src = (lane < NW)
            ? (params_true + ((size_t)b * NW + lane) * 6)
            : (params_pred + ((size_t)b * NW + (lane - NW)) * 6);
        float sx = src[0], sy = src[1], ex = src[2], ey = src[3];
        float w  = src[4], prob = src[5];

        float dx = ex - sx, dy = ey - sy;
        float cx = (sx + ex) * 0.5f, cy = (sy + ey) * 0.5f;
        float len = sqrtf(dx * dx + dy * dy);
        float area = len * w;

        float smaller = fminf(w, len), bigger = fmaxf(w, len);
        float sr = (bigger > 0.0f) ? (smaller / bigger) : 0.0f;

        float px = dy, py = -dx;
        float pd = len;
        if (pd > 0.0f) { px /= pd; py /= pd; }
        px *= w * 0.5f; py *= w * 0.5f;
        float right = fmaxf(fmaxf(sx + px, sx - px), fmaxf(ex + px, ex - px));
        float top   = fmaxf(fmaxf(sy + py, sy - py), fmaxf(ey + py, ey - py));
        float bbw = fabsf((right - cx) * 2.0f);
        float bbh = fabsf((top   - cy) * 2.0f);
        float bba = bbw * bbh;
        float ar  = (bba > 0.001f) ? (area / bba) : 1.0f;

        float* f = (lane < NW) ? featT[lane] : featP[lane - NW];
        f[0] = cx;  f[1] = cy;  f[2] = area; f[3] = sr;
        f[4] = ar;  f[5] = bbw; f[6] = bbh;  f[7] = prob;
    }
    __syncthreads();

    // ---------------- Phase 2: 32x32 cost matrix (16 entries/lane) -------------
    for (int e = lane; e < NW * NW; e += 64) {
        int i = e >> 5, j = e & 31;
        float dcx = featT[i][0] - featP[j][0];
        float dcy = featT[i][1] - featP[j][1];
        float center_d = dcx * dcx + dcy * dcy;
        float da = featT[i][2] - featP[j][2];   float area_d  = da * da;
        float ds = featT[i][3] - featP[j][3];   float lwr_d   = ds * ds;
        float dr = featT[i][4] - featP[j][4];   float rot_d   = dr * dr;
        float dxw = featT[i][5] - featP[j][5];  float horiz_d = dxw * dxw;
        float dyh = featT[i][6] - featP[j][6];  float vert_d  = dyh * dyh;
        float probt = featT[i][7], probp = featP[j][7];
        float dp = probt - probp;               float prob_d  = dp * dp;
        float param_d = area_d + center_d + rot_d + horiz_d + vert_d + lwr_d;
        cost[i][j] = 10.0f * prob_d + param_d * probt;
    }
    __syncthreads();

    // Register-resident cost column as NAMED scalars (no arrays -> no alloca
    // -> guaranteed VGPR residency; R4's array version spilled to scratch,
    // 2 GB of WRITE_SIZE). Lane l holds cost[k][l&31] for k=0..31.
    const int col = lane & 31;
#define LOADC(k) const float c##k = cost[k][col];
    LOADC(0)  LOADC(1)  LOADC(2)  LOADC(3)  LOADC(4)  LOADC(5)  LOADC(6)  LOADC(7)
    LOADC(8)  LOADC(9)  LOADC(10) LOADC(11) LOADC(12) LOADC(13) LOADC(14) LOADC(15)
    LOADC(16) LOADC(17) LOADC(18) LOADC(19) LOADC(20) LOADC(21) LOADC(22) LOADC(23)
    LOADC(24) LOADC(25) LOADC(26) LOADC(27) LOADC(28) LOADC(29) LOADC(30) LOADC(31)
#undef LOADC

    // ---------------- Phase 3: Hungarian (JV SAP), one wave per batch ----------
    const bool isCol = lane < NW;
    float v_col   = 0.0f;
    float u_row   = 0.0f;
    int   row4col = -1;
    int   col4row = -1;

    for (int i0 = 0; i0 < NW; ++i0) {
        bool  SCb   = !isCol;       // lanes >=32: permanently excluded
        float spc   = BIGF;
        int   path  = -1;
        unsigned srMask = 0;        // scalar bitmask of SR rows
        float minVal = 0.0f;        // scalar
        int   i = i0;               // scalar
        int   sink;

        while (true) {
            srMask |= (1u << i);

            // cij = c{i} via 5-level cndmask tree on uniform bits of i.
            const bool b0 = i & 1, b1 = i & 2, b2 = i & 4, b3 = i & 8, b4 = i & 16;
            float a0  = b0 ? c1  : c0;   float a1  = b0 ? c3  : c2;
            float a2  = b0 ? c5  : c4;   float a3  = b0 ? c7  : c6;
            float a4  = b0 ? c9  : c8;   float a5  = b0 ? c11 : c10;
            float a6  = b0 ? c13 : c12;  float a7  = b0 ? c15 : c14;
            float a8  = b0 ? c17 : c16;  float a9  = b0 ? c19 : c18;
            float a10 = b0 ? c21 : c20;  float a11 = b0 ? c23 : c22;
            float a12 = b0 ? c25 : c24;  float a13 = b0 ? c27 : c26;
            float a14 = b0 ? c29 : c28;  float a15 = b0 ? c31 : c30;
            float d0 = b1 ? a1  : a0;    float d1 = b1 ? a3  : a2;
            float d2 = b1 ? a5  : a4;    float d3 = b1 ? a7  : a6;
            float d4 = b1 ? a9  : a8;    float d5 = b1 ? a11 : a10;
            float d6 = b1 ? a13 : a12;   float d7 = b1 ? a15 : a14;
            float e0 = b2 ? d1 : d0;     float e1 = b2 ? d3 : d2;
            float e2 = b2 ? d5 : d4;     float e3 = b2 ? d7 : d6;
            float f0 = b3 ? e1 : e0;     float f1 = b3 ? e3 : e2;
            float cij = b4 ? f1 : f0;

            float u_i   = readlane_f(u_row, i);                  // scalar
            float slack = minVal + cij - u_i - v_col;            // same assoc. as ref
            bool better = (!SCb) && (slack < spc);
            if (better) { spc = slack; path = i; }
            float spcRed = SCb ? BIGF : spc;                     // masked for argmin

            float mv = wave_min32(spcRed);                       // scalar min
            unsigned long long hit = __ballot(spcRed == mv);     // exact-bit match
            int j = __ffsll(hit) - 1;                            // lowest index tie-break
            minVal = mv;
            if (lane == j) SCb = true;
            int r = __builtin_amdgcn_readlane(row4col, j);       // scalar
            if (r < 0) { sink = j; break; }
            i = r;
        }

        // potential updates
        {
            int gidx = (col4row < 0) ? 0 : col4row;
            float spc_at_c4r = __shfl(spc, gidx);                // per-lane index
            bool in_SR = isCol && ((srMask >> (lane & 31)) & 1u);
            if (lane == i0)              u_row += minVal;
            else if (in_SR)              u_row += minVal - spc_at_c4r;
            if (isCol && SCb)            v_col -= (minVal - spc);
        }

        // augment along path (scalar walk)
        {
            int j = sink;
            while (true) {
                int ii = __builtin_amdgcn_readlane(path, j);
                if (lane == j) row4col = ii;
                int j_next = __builtin_amdgcn_readlane(col4row, ii);
                if (lane == ii) col4row = j;
                if (ii == i0) break;
                j = j_next;
            }
        }
    }

    // ---------------- Phase 4: loss = sum of assigned edge costs ---------------
    float myedge = (isCol && col4row >= 0) ? cost[lane][col4row] : 0.0f;
    #pragma unroll
    for (int off = 32; off >= 1; off >>= 1)
        myedge += __shfl_xor(myedge, off);
    if (lane == 0) out[b] = myedge;
}

extern "C" void kernel_launch(void* const* d_in, const int* in_sizes, int n_in,
                              void* d_out, int out_size, void* d_ws, size_t ws_size,
                              hipStream_t stream) {
    const float* params_true = (const float*)d_in[0];
    const float* params_pred = (const float*)d_in[1];
    float* out = (float*)d_out;
    floorplan_hungarian_kernel<<<BATCH, 64, 0, stream>>>(params_true, params_pred, out);
}

// Round 6
// 163.524 us; speedup vs baseline: 4.8941x; 1.0440x over previous
//
#include <hip/hip_runtime.h>

#define NW 32
#define BATCH 2048
#define BIGF 1e9f

// One DPP min step: ctrl/row_mask as template params (must be ICEs).
// bound_ctrl=false => lanes with invalid source keep old value (min identity).
template <int CTRL, int ROW_MASK>
__device__ __forceinline__ float dpp_min_step(float x) {
    int xi = __float_as_int(x);
    int ti = __builtin_amdgcn_update_dpp(xi, xi, CTRL, ROW_MASK, 0xF, false);
    return fminf(x, __int_as_float(ti));
}

// Min over lanes 0..31 (lanes 32..63 must hold BIGF), wave-uniform result.
__device__ __forceinline__ float wave_min32(float x) {
    x = dpp_min_step<0x111, 0xF>(x); // row_shr:1
    x = dpp_min_step<0x112, 0xF>(x); // row_shr:2
    x = dpp_min_step<0x114, 0xF>(x); // row_shr:4
    x = dpp_min_step<0x118, 0xF>(x); // row_shr:8
    x = dpp_min_step<0x142, 0xA>(x); // row_bcast:15 -> rows 1,3
    return __int_as_float(__builtin_amdgcn_readlane(__float_as_int(x), 31));
}

__device__ __forceinline__ float readlane_f(float v, int lane) {
    return __int_as_float(__builtin_amdgcn_readlane(__float_as_int(v), lane));
}

__global__ __launch_bounds__(64) void floorplan_hungarian_kernel(
    const float* __restrict__ params_true,
    const float* __restrict__ params_pred,
    float* __restrict__ out)
{
    const int b    = blockIdx.x;
    const int lane = threadIdx.x;           // 0..63, one full wave

    __shared__ float cost[NW][NW + 1];      // padded rows: conflict-free
    __shared__ float featT[NW][9];
    __shared__ float featP[NW][9];

    // ---------------- Phase 1: per-wall features (1 wall per lane) -------------
    {
        const float* src = (lane < NW)
            ? (params_true + ((size_t)b * NW + lane) * 6)
            : (params_pred + ((size_t)b * NW + (lane - NW)) * 6);
        float sx = src[0], sy = src[1], ex = src[2], ey = src[3];
        float w  = src[4], prob = src[5];

        float dx = ex - sx, dy = ey - sy;
        float cx = (sx + ex) * 0.5f, cy = (sy + ey) * 0.5f;
        float len = sqrtf(dx * dx + dy * dy);
        float area = len * w;

        float smaller = fminf(w, len), bigger = fmaxf(w, len);
        float sr = (bigger > 0.0f) ? (smaller / bigger) : 0.0f;

        float px = dy, py = -dx;
        float pd = len;
        if (pd > 0.0f) { px /= pd; py /= pd; }
        px *= w * 0.5f; py *= w * 0.5f;
        float right = fmaxf(fmaxf(sx + px, sx - px), fmaxf(ex + px, ex - px));
        float top   = fmaxf(fmaxf(sy + py, sy - py), fmaxf(ey + py, ey - py));
        float bbw = fabsf((right - cx) * 2.0f);
        float bbh = fabsf((top   - cy) * 2.0f);
        float bba = bbw * bbh;
        float ar  = (bba > 0.001f) ? (area / bba) : 1.0f;

        float* f = (lane < NW) ? featT[lane] : featP[lane - NW];
        f[0] = cx;  f[1] = cy;  f[2] = area; f[3] = sr;
        f[4] = ar;  f[5] = bbw; f[6] = bbh;  f[7] = prob;
    }
    __syncthreads();

    // ---------------- Phase 2: 32x32 cost matrix (16 entries/lane) -------------
    for (int e = lane; e < NW * NW; e += 64) {
        int i = e >> 5, j = e & 31;
        float dcx = featT[i][0] - featP[j][0];
        float dcy = featT[i][1] - featP[j][1];
        float center_d = dcx * dcx + dcy * dcy;
        float da = featT[i][2] - featP[j][2];   float area_d  = da * da;
        float ds = featT[i][3] - featP[j][3];   float lwr_d   = ds * ds;
        float dr = featT[i][4] - featP[j][4];   float rot_d   = dr * dr;
        float dxw = featT[i][5] - featP[j][5];  float horiz_d = dxw * dxw;
        float dyh = featT[i][6] - featP[j][6];  float vert_d  = dyh * dyh;
        float probt = featT[i][7], probp = featP[j][7];
        float dp = probt - probp;               float prob_d  = dp * dp;
        float param_d = area_d + center_d + rot_d + horiz_d + vert_d + lwr_d;
        cost[i][j] = 10.0f * prob_d + param_d * probt;
    }
    __syncthreads();

    // Register-resident cost column: lane l holds cost[k][l&31], k=0..31.
    // NAMED scalars + empty asm "+v" barrier: forces VGPR residency and makes
    // the values opaque so the compiler can neither spill them (R4: scratch,
    // 2 GB writes) nor fold the select tree back into an indexed ds_read
    // (R5: same bank conflicts & VGPR=36 as R3, chain fully exposed).
    const int col = lane & 31;
#define LOADC(k) float c##k = cost[k][col];
    LOADC(0)  LOADC(1)  LOADC(2)  LOADC(3)  LOADC(4)  LOADC(5)  LOADC(6)  LOADC(7)
    LOADC(8)  LOADC(9)  LOADC(10) LOADC(11) LOADC(12) LOADC(13) LOADC(14) LOADC(15)
    LOADC(16) LOADC(17) LOADC(18) LOADC(19) LOADC(20) LOADC(21) LOADC(22) LOADC(23)
    LOADC(24) LOADC(25) LOADC(26) LOADC(27) LOADC(28) LOADC(29) LOADC(30) LOADC(31)
#undef LOADC
    asm volatile("" : "+v"(c0),  "+v"(c1),  "+v"(c2),  "+v"(c3),
                      "+v"(c4),  "+v"(c5),  "+v"(c6),  "+v"(c7));
    asm volatile("" : "+v"(c8),  "+v"(c9),  "+v"(c10), "+v"(c11),
                      "+v"(c12), "+v"(c13), "+v"(c14), "+v"(c15));
    asm volatile("" : "+v"(c16), "+v"(c17), "+v"(c18), "+v"(c19),
                      "+v"(c20), "+v"(c21), "+v"(c22), "+v"(c23));
    asm volatile("" : "+v"(c24), "+v"(c25), "+v"(c26), "+v"(c27),
                      "+v"(c28), "+v"(c29), "+v"(c30), "+v"(c31));

    // ---------------- Phase 3: Hungarian (JV SAP), one wave per batch ----------
    const bool isCol = lane < NW;
    float v_col   = 0.0f;
    float u_row   = 0.0f;
    int   row4col = -1;
    int   col4row = -1;

    for (int i0 = 0; i0 < NW; ++i0) {
        bool  SCb   = !isCol;       // lanes >=32: permanently excluded
        float spc   = BIGF;
        int   path  = -1;
        unsigned srMask = 0;        // scalar bitmask of SR rows
        float minVal = 0.0f;        // scalar
        int   i = i0;               // scalar
        int   sink;

        while (true) {
            srMask |= (1u << i);

            // cij = c{i} via 5-level cndmask tree on uniform bits of i.
            const bool b0 = i & 1, b1 = i & 2, b2 = i & 4, b3 = i & 8, b4 = i & 16;
            float a0  = b0 ? c1  : c0;   float a1  = b0 ? c3  : c2;
            float a2  = b0 ? c5  : c4;   float a3  = b0 ? c7  : c6;
            float a4  = b0 ? c9  : c8;   float a5  = b0 ? c11 : c10;
            float a6  = b0 ? c13 : c12;  float a7  = b0 ? c15 : c14;
            float a8  = b0 ? c17 : c16;  float a9  = b0 ? c19 : c18;
            float a10 = b0 ? c21 : c20;  float a11 = b0 ? c23 : c22;
            float a12 = b0 ? c25 : c24;  float a13 = b0 ? c27 : c26;
            float a14 = b0 ? c29 : c28;  float a15 = b0 ? c31 : c30;
            float d0 = b1 ? a1  : a0;    float d1 = b1 ? a3  : a2;
            float d2 = b1 ? a5  : a4;    float d3 = b1 ? a7  : a6;
            float d4 = b1 ? a9  : a8;    float d5 = b1 ? a11 : a10;
            float d6 = b1 ? a13 : a12;   float d7 = b1 ? a15 : a14;
            float e0 = b2 ? d1 : d0;     float e1 = b2 ? d3 : d2;
            float e2 = b2 ? d5 : d4;     float e3 = b2 ? d7 : d6;
            float f0 = b3 ? e1 : e0;     float f1 = b3 ? e3 : e2;
            float cij = b4 ? f1 : f0;

            float u_i   = readlane_f(u_row, i);                  // scalar
            float slack = minVal + cij - u_i - v_col;            // same assoc. as ref
            bool better = (!SCb) && (slack < spc);
            if (better) { spc = slack; path = i; }
            float spcRed = SCb ? BIGF : spc;                     // masked for argmin

            float mv = wave_min32(spcRed);                       // scalar min
            unsigned long long hit = __ballot(spcRed == mv);     // exact-bit match
            int j = __ffsll(hit) - 1;                            // lowest index tie-break
            minVal = mv;
            if (lane == j) SCb = true;
            int r = __builtin_amdgcn_readlane(row4col, j);       // scalar
            if (r < 0) { sink = j; break; }
            i = r;
        }

        // potential updates
        {
            int gidx = (col4row < 0) ? 0 : col4row;
            float spc_at_c4r = __shfl(spc, gidx);                // per-lane index
            bool in_SR = isCol && ((srMask >> (lane & 31)) & 1u);
            if (lane == i0)              u_row += minVal;
            else if (in_SR)              u_row += minVal - spc_at_c4r;
            if (isCol && SCb)            v_col -= (minVal - spc);
        }

        // augment along path (scalar walk)
        {
            int j = sink;
            while (true) {
                int ii = __builtin_amdgcn_readlane(path, j);
                if (lane == j) row4col = ii;
                int j_next = __builtin_amdgcn_readlane(col4row, ii);
                if (lane == ii) col4row = j;
                if (ii == i0) break;
                j = j_next;
            }
        }
    }

    // ---------------- Phase 4: loss = sum of assigned edge costs ---------------
    float myedge = (isCol && col4row >= 0) ? cost[lane][col4row] : 0.0f;
    #pragma unroll
    for (int off = 32; off >= 1; off >>= 1)
        myedge += __shfl_xor(myedge, off);
    if (lane == 0) out[b] = myedge;
}

extern "C" void kernel_launch(void* const* d_in, const int* in_sizes, int n_in,
                              void* d_out, int out_size, void* d_ws, size_t ws_size,
                              hipStream_t stream) {
    const float* params_true = (const float*)d_in[0];
    const float* params_pred = (const float*)d_in[1];
    float* out = (float*)d_out;
    floorplan_hungarian_kernel<<<BATCH, 64, 0, stream>>>(params_true, params_pred, out);
}

// Round 7
// 143.885 us; speedup vs baseline: 5.5621x; 1.1365x over previous
//
#include <hip/hip_runtime.h>

#define NW 32
#define BATCH 2048
#define BIGF 1e9f

// One DPP min step: ctrl/row_mask as template params (must be ICEs).
// update_dpp(old, src, ...): lanes with invalid source get 'old' (= x), the
// identity for min.
template <int CTRL, int ROW_MASK>
__device__ __forceinline__ float dpp_min_step(float x) {
    int xi = __float_as_int(x);
    int ti = __builtin_amdgcn_update_dpp(xi, xi, CTRL, ROW_MASK, 0xF, false);
    return fminf(x, __int_as_float(ti));
}

// Min over lanes 0..31 (lanes 32..63 must hold BIGF), wave-uniform result.
__device__ __forceinline__ float wave_min32(float x) {
    x = dpp_min_step<0x111, 0xF>(x); // row_shr:1
    x = dpp_min_step<0x112, 0xF>(x); // row_shr:2
    x = dpp_min_step<0x114, 0xF>(x); // row_shr:4
    x = dpp_min_step<0x118, 0xF>(x); // row_shr:8
    x = dpp_min_step<0x142, 0xA>(x); // row_bcast:15 -> rows 1,3
    return __int_as_float(__builtin_amdgcn_readlane(__float_as_int(x), 31));
}

__device__ __forceinline__ float readlane_f(float v, int lane) {
    return __int_as_float(__builtin_amdgcn_readlane(__float_as_int(v), lane));
}

__global__ __launch_bounds__(64) void floorplan_hungarian_kernel(
    const float* __restrict__ params_true,
    const float* __restrict__ params_pred,
    float* __restrict__ out)
{
    const int b    = blockIdx.x;
    const int lane = threadIdx.x;           // 0..63, one full wave

    __shared__ float cost[NW][NW + 1];      // padded rows: conflict-free
    __shared__ float featT[NW][9];
    __shared__ float featP[NW][9];
    __shared__ int   rw[NW];                // CR row-winner scratch

    // ---------------- Phase 1: per-wall features (1 wall per lane) -------------
    {
        const float* src = (lane < NW)
            ? (params_true + ((size_t)b * NW + lane) * 6)
            : (params_pred + ((size_t)b * NW + (lane - NW)) * 6);
        float sx = src[0], sy = src[1], ex = src[2], ey = src[3];
        float w  = src[4], prob = src[5];

        float dx = ex - sx, dy = ey - sy;
        float cx = (sx + ex) * 0.5f, cy = (sy + ey) * 0.5f;
        float len = sqrtf(dx * dx + dy * dy);
        float area = len * w;

        float smaller = fminf(w, len), bigger = fmaxf(w, len);
        float sr = (bigger > 0.0f) ? (smaller / bigger) : 0.0f;

        float px = dy, py = -dx;
        float pd = len;
        if (pd > 0.0f) { px /= pd; py /= pd; }
        px *= w * 0.5f; py *= w * 0.5f;
        float right = fmaxf(fmaxf(sx + px, sx - px), fmaxf(ex + px, ex - px));
        float top   = fmaxf(fmaxf(sy + py, sy - py), fmaxf(ey + py, ey - py));
        float bbw = fabsf((right - cx) * 2.0f);
        float bbh = fabsf((top   - cy) * 2.0f);
        float bba = bbw * bbh;
        float ar  = (bba > 0.001f) ? (area / bba) : 1.0f;

        float* f = (lane < NW) ? featT[lane] : featP[lane - NW];
        f[0] = cx;  f[1] = cy;  f[2] = area; f[3] = sr;
        f[4] = ar;  f[5] = bbw; f[6] = bbh;  f[7] = prob;
    }
    __syncthreads();

    // ------- Phase 2: 32x32 cost matrix + fused column-min (CR part 1) --------
    // lane L handles column j = L&31, rows {2t + (L>=32)} for t=0..15.
    float cmin = BIGF; int cargmin = 0;
    for (int e = lane; e < NW * NW; e += 64) {
        int i = e >> 5, j = e & 31;
        float dcx = featT[i][0] - featP[j][0];
        float dcy = featT[i][1] - featP[j][1];
        float center_d = dcx * dcx + dcy * dcy;
        float da = featT[i][2] - featP[j][2];   float area_d  = da * da;
        float ds = featT[i][3] - featP[j][3];   float lwr_d   = ds * ds;
        float dr = featT[i][4] - featP[j][4];   float rot_d   = dr * dr;
        float dxw = featT[i][5] - featP[j][5];  float horiz_d = dxw * dxw;
        float dyh = featT[i][6] - featP[j][6];  float vert_d  = dyh * dyh;
        float probt = featT[i][7], probp = featP[j][7];
        float dp = probt - probp;               float prob_d  = dp * dp;
        float param_d = area_d + center_d + rot_d + horiz_d + vert_d + lwr_d;
        float val = 10.0f * prob_d + param_d * probt;
        cost[i][j] = val;
        if (val < cmin) { cmin = val; cargmin = i; }   // rows ascending: first-min
    }
    // merge even-row half with odd-row half of the same column
    {
        float om = __shfl_xor(cmin, 32);
        int   oi = __shfl_xor(cargmin, 32);
        if (om < cmin || (om == cmin && oi < cargmin)) { cmin = om; cargmin = oi; }
    }
    if (lane < NW) rw[lane] = -1;
    __syncthreads();

    // ---------------- CR part 2: greedy unique-argmin assignment ---------------
    if (lane < NW) rw[cargmin] = lane;      // column 'lane' proposes row cargmin
    __syncthreads();

    const bool isCol = lane < NW;
    float v_col   = isCol ? cmin : 0.0f;    // column reduction duals
    float u_row   = 0.0f;                   // CR-assigned rows stay u=0 (tight)
    int   row4col = -1;
    int   col4row = -1;
    if (isCol) {
        if (rw[lane] >= 0)        col4row = rw[lane];     // row role
        if (rw[cargmin] == lane)  row4col = cargmin;      // col role: won
    }
    __syncthreads();

    // ---------------- ART: augmenting row reduction (serial, cheap) ------------
    // Maintains dual feasibility: u[i]=usubmin, v[j1]-=(usubmin-umin);
    // assigned edges tight, reduced costs >= 0, v only decreases.
    {
        unsigned freeRows =
            (unsigned)(__ballot(isCol && col4row < 0) & 0xffffffffull);
        int steps = 0;
        while (freeRows != 0 && steps < 96) {
            int i = __ffs(freeRows) - 1;
            freeRows &= (freeRows - 1);
            bool chain = true;
            while (chain && steps < 96) {
                ++steps;
                float r  = isCol ? (cost[i][lane] - v_col) : BIGF;
                float m1 = wave_min32(r);
                unsigned long long h1 = __ballot(r == m1);
                int j1 = __ffsll(h1) - 1;
                float r2 = (lane == j1) ? BIGF : r;
                float m2 = wave_min32(r2);

                int jt = j1;
                if (m1 < m2) {
                    if (lane == j1) v_col -= (m2 - m1);
                } else {
                    // tie: prefer a free column to avoid swap cycles
                    unsigned long long h2 = __ballot(r2 == m2);
                    int j2 = __ffsll(h2) - 1;
                    int r4c1 = __builtin_amdgcn_readlane(row4col, j1);
                    if (r4c1 >= 0) jt = j2;
                }
                if (lane == i) u_row = m2;    // usubmin keeps feasibility

                int iold = __builtin_amdgcn_readlane(row4col, jt);
                if (lane == jt)  row4col = i;
                if (lane == iold) col4row = -1;   // displaced row freed
                if (lane == i)   col4row = jt;
                if (iold >= 0) i = iold; else chain = false;
            }
        }
    }

    // ---------------- SAP: shortest augmenting path for leftover rows ----------
    {
        unsigned rem = (unsigned)(__ballot(isCol && col4row < 0) & 0xffffffffull);
        while (rem != 0) {
            int i0 = __ffs(rem) - 1;
            rem &= (rem - 1);

            bool  SCb   = !isCol;
            float spc   = BIGF;
            int   path  = -1;
            unsigned srMask = 0;
            float minVal = 0.0f;
            int   i = i0;
            int   sink;

            float cij = isCol ? cost[i][lane] : 0.0f;   // prefetched cost row
            while (true) {
                srMask |= (1u << i);
                float u_i   = readlane_f(u_row, i);
                float slack = minVal + cij - u_i - v_col;
                bool better = (!SCb) && (slack < spc);
                if (better) { spc = slack; path = i; }
                float spcRed = SCb ? BIGF : spc;

                float mv = wave_min32(spcRed);
                unsigned long long hit = __ballot(spcRed == mv);
                int j = __ffsll(hit) - 1;
                minVal = mv;
                if (lane == j) SCb = true;
                int r = __builtin_amdgcn_readlane(row4col, j);
                if (r < 0) { sink = j; break; }
                i = r;
                cij = isCol ? cost[i][lane] : 0.0f;     // prefetch next row
            }

            // dual updates
            {
                int gidx = (col4row < 0) ? 0 : col4row;
                float spc_at_c4r = __shfl(spc, gidx);
                bool in_SR = isCol && ((srMask >> (lane & 31)) & 1u);
                if (lane == i0)              u_row += minVal;
                else if (in_SR)              u_row += minVal - spc_at_c4r;
                if (isCol && SCb)            v_col -= (minVal - spc);
            }

            // augment along path
            {
                int j = sink;
                while (true) {
                    int ii = __builtin_amdgcn_readlane(path, j);
                    if (lane == j) row4col = ii;
                    int j_next = __builtin_amdgcn_readlane(col4row, ii);
                    if (lane == ii) col4row = j;
                    if (ii == i0) break;
                    j = j_next;
                }
            }
        }
    }

    // ---------------- Loss = sum of assigned true edge costs -------------------
    float myedge = (isCol && col4row >= 0) ? cost[lane][col4row] : 0.0f;
    #pragma unroll
    for (int off = 32; off >= 1; off >>= 1)
        myedge += __shfl_xor(myedge, off);
    if (lane == 0) out[b] = myedge;
}

extern "C" void kernel_launch(void* const* d_in, const int* in_sizes, int n_in,
                              void* d_out, int out_size, void* d_ws, size_t ws_size,
                              hipStream_t stream) {
    const float* params_true = (const float*)d_in[0];
    const float* params_pred = (const float*)d_in[1];
    float* out = (float*)d_out;
    floorplan_hungarian_kernel<<<BATCH, 64, 0, stream>>>(params_true, params_pred, out);
}

// Round 8
// 116.617 us; speedup vs baseline: 6.8627x; 1.2338x over previous
//
#include <hip/hip_runtime.h>

#define NW 32
#define BATCH 2048
#define BIGF 1e9f

// One DPP min step: ctrl/row_mask as template params (must be ICEs).
// update_dpp(old=x, src=x): invalid-source lanes get old (= x), min identity.
template <int CTRL, int ROW_MASK>
__device__ __forceinline__ float dpp_min_step(float x) {
    int xi = __float_as_int(x);
    int ti = __builtin_amdgcn_update_dpp(xi, xi, CTRL, ROW_MASK, 0xF, false);
    return fminf(x, __int_as_float(ti));
}

// Min over lanes 0..31 (lanes 32..63 must hold BIGF), wave-uniform result.
__device__ __forceinline__ float wave_min32(float x) {
    x = dpp_min_step<0x111, 0xF>(x); // row_shr:1
    x = dpp_min_step<0x112, 0xF>(x); // row_shr:2
    x = dpp_min_step<0x114, 0xF>(x); // row_shr:4
    x = dpp_min_step<0x118, 0xF>(x); // row_shr:8
    x = dpp_min_step<0x142, 0xA>(x); // row_bcast:15 -> rows 1,3
    return __int_as_float(__builtin_amdgcn_readlane(__float_as_int(x), 31));
}

__device__ __forceinline__ float readlane_f(float v, int lane) {
    return __int_as_float(__builtin_amdgcn_readlane(__float_as_int(v), lane));
}

__global__ __launch_bounds__(64) void floorplan_hungarian_kernel(
    const float* __restrict__ params_true,
    const float* __restrict__ params_pred,
    float* __restrict__ out)
{
    const int b    = blockIdx.x;
    const int lane = threadIdx.x;           // 0..63, one full wave

    __shared__ float cost[NW][NW + 1];      // padded rows: conflict-free
    __shared__ float featT[NW][9];
    __shared__ float featP[NW][9];
    __shared__ int   rw[NW];                // CR: winning column per row

    // ---------------- Phase 1: per-wall features (1 wall per lane) -------------
    {
        const float* src = (lane < NW)
            ? (params_true + ((size_t)b * NW + lane) * 6)
            : (params_pred + ((size_t)b * NW + (lane - NW)) * 6);
        float sx = src[0], sy = src[1], ex = src[2], ey = src[3];
        float w  = src[4], prob = src[5];

        float dx = ex - sx, dy = ey - sy;
        float cx = (sx + ex) * 0.5f, cy = (sy + ey) * 0.5f;
        float len = sqrtf(dx * dx + dy * dy);
        float area = len * w;

        float smaller = fminf(w, len), bigger = fmaxf(w, len);
        float sr = (bigger > 0.0f) ? (smaller / bigger) : 0.0f;

        float px = dy, py = -dx;
        float pd = len;
        if (pd > 0.0f) { px /= pd; py /= pd; }
        px *= w * 0.5f; py *= w * 0.5f;
        float right = fmaxf(fmaxf(sx + px, sx - px), fmaxf(ex + px, ex - px));
        float top   = fmaxf(fmaxf(sy + py, sy - py), fmaxf(ey + py, ey - py));
        float bbw = fabsf((right - cx) * 2.0f);
        float bbh = fabsf((top   - cy) * 2.0f);
        float bba = bbw * bbh;
        float ar  = (bba > 0.001f) ? (area / bba) : 1.0f;

        float* f = (lane < NW) ? featT[lane] : featP[lane - NW];
        f[0] = cx;  f[1] = cy;  f[2] = area; f[3] = sr;
        f[4] = ar;  f[5] = bbw; f[6] = bbh;  f[7] = prob;
    }
    if (lane < NW) rw[lane] = 64;           // CR winner init
    __syncthreads();

    // ------- Phase 2: 32x32 cost matrix + fused column-min (CR part 1) --------
    // lane L handles column j = L&31, rows {2t + (L>=32)}.
    float cmin = BIGF; int cargmin = 0;
    for (int e = lane; e < NW * NW; e += 64) {
        int i = e >> 5, j = e & 31;
        float dcx = featT[i][0] - featP[j][0];
        float dcy = featT[i][1] - featP[j][1];
        float center_d = dcx * dcx + dcy * dcy;
        float da = featT[i][2] - featP[j][2];   float area_d  = da * da;
        float ds = featT[i][3] - featP[j][3];   float lwr_d   = ds * ds;
        float dr = featT[i][4] - featP[j][4];   float rot_d   = dr * dr;
        float dxw = featT[i][5] - featP[j][5];  float horiz_d = dxw * dxw;
        float dyh = featT[i][6] - featP[j][6];  float vert_d  = dyh * dyh;
        float probt = featT[i][7], probp = featP[j][7];
        float dp = probt - probp;               float prob_d  = dp * dp;
        float param_d = area_d + center_d + rot_d + horiz_d + vert_d + lwr_d;
        float val = 10.0f * prob_d + param_d * probt;
        cost[i][j] = val;
        if (val < cmin) { cmin = val; cargmin = i; }   // rows ascending: first-min
    }
    // merge even-row half with odd-row half of the same column
    {
        float om = __shfl_xor(cmin, 32);
        int   oi = __shfl_xor(cargmin, 32);
        if (om < cmin || (om == cmin && oi < cargmin)) { cmin = om; cargmin = oi; }
    }
    __syncthreads();

    // --------- CR part 2: deterministic unique-argmin greedy assignment --------
    // Column j proposes its min row; lowest column index wins the row.
    if (lane < NW) atomicMin(&rw[cargmin], lane);
    __syncthreads();

    const bool isCol = lane < NW;
    const int  col   = lane & 31;
    float v_col   = isCol ? cmin : 0.0f;    // v = column min (feasible duals)
    float u_row   = 0.0f;
    int   win     = isCol ? rw[lane] : 64;  // winner column for row 'lane'
    int   col4row = (isCol && win < 64) ? win : -1;
    int   row4col = (isCol && rw[cargmin] == lane) ? cargmin : -1;
    __syncthreads();

    // ---------------- SAP: shortest augmenting path for free rows --------------
    {
        unsigned rem = (unsigned)(__ballot(isCol && col4row < 0) & 0xffffffffull);
        while (rem != 0) {
            int i0 = __ffs(rem) - 1;
            rem &= (rem - 1);

            bool  SCb   = !isCol;
            float spc   = BIGF;
            int   path  = -1;
            unsigned srMask = 0;
            float minVal = 0.0f;
            int   i = i0;
            int   sink;

            float cij = cost[i][col];       // prefetched cost row (dup for hi half)
            while (true) {
                srMask |= (1u << i);
                float u_i   = readlane_f(u_row, i);
                float slack = minVal + cij - u_i - v_col;
                bool better = (!SCb) && (slack < spc);
                if (better) { spc = slack; path = i; }
                float spcRed = SCb ? BIGF : spc;

                float mv = wave_min32(spcRed);
                unsigned long long hit = __ballot(spcRed == mv);
                int j = __ffsll(hit) - 1;
                minVal = mv;
                if (lane == j) SCb = true;
                int r = __builtin_amdgcn_readlane(row4col, j);
                if (r < 0) { sink = j; break; }
                i = r;
                cij = cost[i][col];         // prefetch next row
            }

            // dual updates
            {
                int gidx = (col4row < 0) ? 0 : col4row;
                float spc_at_c4r = __shfl(spc, gidx);
                bool in_SR = isCol && ((srMask >> col) & 1u);
                if (lane == i0)              u_row += minVal;
                else if (in_SR)              u_row += minVal - spc_at_c4r;
                if (isCol && SCb)            v_col -= (minVal - spc);
            }

            // augment along path
            {
                int j = sink;
                while (true) {
                    int ii = __builtin_amdgcn_readlane(path, j);
                    if (lane == j) row4col = ii;
                    int j_next = __builtin_amdgcn_readlane(col4row, ii);
                    if (lane == ii) col4row = j;
                    if (ii == i0) break;
                    j = j_next;
                }
            }
        }
    }

    // ---------------- Loss = sum of assigned edge costs ------------------------
    float myedge = (isCol && col4row >= 0) ? cost[lane][col4row] : 0.0f;
    #pragma unroll
    for (int off = 32; off >= 1; off >>= 1)
        myedge += __shfl_xor(myedge, off);
    if (lane == 0) out[b] = myedge;
}

extern "C" void kernel_launch(void* const* d_in, const int* in_sizes, int n_in,
                              void* d_out, int out_size, void* d_ws, size_t ws_size,
                              hipStream_t stream) {
    const float* params_true = (const float*)d_in[0];
    const float* params_pred = (const float*)d_in[1];
    float* out = (float*)d_out;
    floorplan_hungarian_kernel<<<BATCH, 64, 0, stream>>>(params_true, params_pred, out);
}